// Round 1
// baseline (454.908 us; speedup 1.0000x reference)
//
#include <hip/hip_runtime.h>
#include <hip/hip_bf16.h>

typedef __bf16 bf16x8 __attribute__((ext_vector_type(8)));
typedef float f32x4 __attribute__((ext_vector_type(4)));
typedef unsigned short u16x8 __attribute__((ext_vector_type(8)));
typedef unsigned short u16x4 __attribute__((ext_vector_type(4)));

#define HB 16
#define TT 2048
#define CCH 1024
#define DD 64

__device__ __forceinline__ unsigned short f2bf(float f) {
  union { __hip_bfloat16 h; unsigned short u; } cv;
  cv.h = __float2bfloat16(f);
  return cv.u;
}

__device__ __forceinline__ f32x4 mfma16(bf16x8 a, bf16x8 b, f32x4 c) {
  return __builtin_amdgcn_mfma_f32_16x16x32_bf16(a, b, c, 0, 0, 0);
}

// ---------------- conversion kernels ----------------

__global__ __launch_bounds__(256) void cvt_f32_bf16(const float* __restrict__ in,
                                                    unsigned short* __restrict__ out,
                                                    int n4) {
  int i = blockIdx.x * 256 + threadIdx.x;
  if (i >= n4) return;
  float4 v = reinterpret_cast<const float4*>(in)[i];
  u16x4 o;
  o.x = f2bf(v.x); o.y = f2bf(v.y); o.z = f2bf(v.z); o.w = f2bf(v.w);
  *reinterpret_cast<u16x4*>(out + (size_t)i * 4) = o;
}

// w: [1024 x N] fp32  ->  wt: [N x 1024] bf16 (transposed)
__global__ __launch_bounds__(256) void transpose_cvt(const float* __restrict__ w,
                                                     unsigned short* __restrict__ wt,
                                                     int N) {
  __shared__ unsigned short t[32][33];
  int nb = blockIdx.x * 32, kb = blockIdx.y * 32;
  int tx = threadIdx.x & 31, ty = threadIdx.x >> 5;  // ty 0..7
  #pragma unroll
  for (int r = 0; r < 32; r += 8)
    t[ty + r][tx] = f2bf(w[(size_t)(kb + ty + r) * N + nb + tx]);
  __syncthreads();
  #pragma unroll
  for (int r = 0; r < 32; r += 8)
    wt[(size_t)(nb + ty + r) * 1024 + kb + tx] = t[tx][ty + r];
}

// ---------------- GEMM: C = A @ Bt^T (+bias), bf16 in, fp32 acc ----------------
// A: [M x K] bf16 row-major. Bt: [N x K] bf16 row-major (i.e. B transposed).
// EPI 0: scatter to q/k/v [B,H,T,D] bf16 (q scaled by 0.125).  EPI 1: fp32 out (N=1024).

template <int EPI>
__global__ __launch_bounds__(256) void gemm_bf16(
    const unsigned short* __restrict__ A,
    const unsigned short* __restrict__ Bt,
    const float* __restrict__ bias,
    float* __restrict__ outf,
    unsigned short* __restrict__ qb,
    unsigned short* __restrict__ kb,
    unsigned short* __restrict__ vb,
    int Ktot) {
  __shared__ unsigned short As[128][72];  // +8 pad: 144B row stride -> conflict-free-ish
  __shared__ unsigned short Bs[128][72];
  const int tid = threadIdx.x;
  const int lane = tid & 63;
  const int wid = tid >> 6;
  const int r16 = lane & 15, g = lane >> 4;
  const int wm = wid >> 1, wn = wid & 1;
  const int m0 = blockIdx.y * 128, n0 = blockIdx.x * 128;

  f32x4 acc[4][4];
  #pragma unroll
  for (int i = 0; i < 4; ++i)
    #pragma unroll
    for (int j = 0; j < 4; ++j) acc[i][j] = (f32x4){0.f, 0.f, 0.f, 0.f};

  for (int kt = 0; kt < Ktot; kt += 64) {
    #pragma unroll
    for (int it = 0; it < 4; ++it) {
      int chunk = it * 256 + tid;
      int row = chunk >> 3, c8 = (chunk & 7) * 8;
      *reinterpret_cast<u16x8*>(&As[row][c8]) =
          *reinterpret_cast<const u16x8*>(&A[(size_t)(m0 + row) * Ktot + kt + c8]);
      *reinterpret_cast<u16x8*>(&Bs[row][c8]) =
          *reinterpret_cast<const u16x8*>(&Bt[(size_t)(n0 + row) * Ktot + kt + c8]);
    }
    __syncthreads();
    #pragma unroll
    for (int kk = 0; kk < 64; kk += 32) {
      bf16x8 af[4], bfr[4];
      #pragma unroll
      for (int i = 0; i < 4; ++i)
        af[i] = *reinterpret_cast<const bf16x8*>(&As[wm * 64 + i * 16 + r16][kk + g * 8]);
      #pragma unroll
      for (int j = 0; j < 4; ++j)
        bfr[j] = *reinterpret_cast<const bf16x8*>(&Bs[wn * 64 + j * 16 + r16][kk + g * 8]);
      #pragma unroll
      for (int i = 0; i < 4; ++i)
        #pragma unroll
        for (int j = 0; j < 4; ++j)
          acc[i][j] = mfma16(af[i], bfr[j], acc[i][j]);
    }
    __syncthreads();
  }

  #pragma unroll
  for (int i = 0; i < 4; ++i) {
    #pragma unroll
    for (int j = 0; j < 4; ++j) {
      #pragma unroll
      for (int r = 0; r < 4; ++r) {
        int m = m0 + wm * 64 + i * 16 + g * 4 + r;
        int n = n0 + wn * 64 + j * 16 + r16;
        float v = acc[i][j][r] + bias[n];
        if (EPI == 1) {
          outf[(size_t)m * 1024 + n] = v;
        } else {
          int which = n >> 10;
          int cc2 = n & 1023;
          int h = cc2 >> 6, d = cc2 & 63;
          int b = m >> 11, t = m & 2047;
          unsigned short* dst = (which == 0) ? qb : (which == 1) ? kb : vb;
          float sc = (which == 0) ? 0.125f : 1.0f;  // fold 1/sqrt(64) into q
          dst[(((size_t)b * HB + h) * TT + t) * DD + d] = f2bf(v * sc);
        }
      }
    }
  }
}

// ---------------- flash attention ----------------
// grid: (T/64, B*H), 256 thr. Wave w owns 16 q-rows; independent waves (no __syncthreads).

__global__ __launch_bounds__(256) void attn_kernel(
    const unsigned short* __restrict__ qg_,
    const unsigned short* __restrict__ kg_,
    const unsigned short* __restrict__ vg_,
    unsigned short* __restrict__ yb) {
  const int bh = blockIdx.y;
  const int wid = threadIdx.x >> 6;
  const int lane = threadIdx.x & 63;
  const int r16 = lane & 15, g = lane >> 4;
  const int qw = blockIdx.x * 64 + wid * 16;
  const unsigned short* Q = qg_ + (size_t)bh * TT * DD;
  const unsigned short* K = kg_ + (size_t)bh * TT * DD;
  const unsigned short* V = vg_ + (size_t)bh * TT * DD;

  __shared__ unsigned short Pl[4][16][40];  // per-wave P staging, padded (80B row)

  // Q fragments (q already scaled by 0.125): A-frag row=r16, k-slice per g
  bf16x8 qf0 = *reinterpret_cast<const bf16x8*>(&Q[(size_t)(qw + r16) * DD + g * 8]);
  bf16x8 qf1 = *reinterpret_cast<const bf16x8*>(&Q[(size_t)(qw + r16) * DD + 32 + g * 8]);

  f32x4 yacc[4];
  #pragma unroll
  for (int db = 0; db < 4; ++db) yacc[db] = (f32x4){0.f, 0.f, 0.f, 0.f};
  float mrow[4], lrow[4];
  #pragma unroll
  for (int r = 0; r < 4; ++r) { mrow[r] = -1e30f; lrow[r] = 0.f; }

  const int kvend = qw + 16;
  for (int kvb = 0; kvb < kvend; kvb += 32) {
    // K fragments: B-operand of S = Q @ K^T  (col = r16 -> kv index, k-slice -> d)
    bf16x8 kf0a = *reinterpret_cast<const bf16x8*>(&K[(size_t)(kvb + r16) * DD + g * 8]);
    bf16x8 kf0b = *reinterpret_cast<const bf16x8*>(&K[(size_t)(kvb + r16) * DD + 32 + g * 8]);
    bf16x8 kf1a = *reinterpret_cast<const bf16x8*>(&K[(size_t)(kvb + 16 + r16) * DD + g * 8]);
    bf16x8 kf1b = *reinterpret_cast<const bf16x8*>(&K[(size_t)(kvb + 16 + r16) * DD + 32 + g * 8]);
    f32x4 s0 = (f32x4){0.f, 0.f, 0.f, 0.f}, s1 = s0;
    s0 = mfma16(qf0, kf0a, s0);
    s0 = mfma16(qf1, kf0b, s0);
    s1 = mfma16(qf0, kf1a, s1);
    s1 = mfma16(qf1, kf1b, s1);

    // C-layout: row(q) = 4*g + r, col(kv) = r16
    float p0[4], p1[4], mx[4];
    #pragma unroll
    for (int r = 0; r < 4; ++r) {
      int q = qw + 4 * g + r;
      p0[r] = (kvb + r16 > q) ? -1e30f : s0[r];
      p1[r] = (kvb + 16 + r16 > q) ? -1e30f : s1[r];
      mx[r] = fmaxf(p0[r], p1[r]);
    }
    #pragma unroll
    for (int sh = 1; sh < 16; sh <<= 1) {
      #pragma unroll
      for (int r = 0; r < 4; ++r) mx[r] = fmaxf(mx[r], __shfl_xor(mx[r], sh));
    }
    float al[4], rs[4];
    #pragma unroll
    for (int r = 0; r < 4; ++r) {
      float mn = fmaxf(mrow[r], mx[r]);
      al[r] = __expf(mrow[r] - mn);
      mrow[r] = mn;
      p0[r] = __expf(p0[r] - mn);
      p1[r] = __expf(p1[r] - mn);
      rs[r] = p0[r] + p1[r];
    }
    #pragma unroll
    for (int sh = 1; sh < 16; sh <<= 1) {
      #pragma unroll
      for (int r = 0; r < 4; ++r) rs[r] += __shfl_xor(rs[r], sh);
    }
    #pragma unroll
    for (int r = 0; r < 4; ++r) lrow[r] = lrow[r] * al[r] + rs[r];
    #pragma unroll
    for (int db = 0; db < 4; ++db)
      #pragma unroll
      for (int r = 0; r < 4; ++r) yacc[db][r] *= al[r];

    // stage P (bf16) into per-wave LDS, re-read in A-fragment layout
    #pragma unroll
    for (int r = 0; r < 4; ++r) {
      Pl[wid][4 * g + r][r16] = f2bf(p0[r]);
      Pl[wid][4 * g + r][16 + r16] = f2bf(p1[r]);
    }
    asm volatile("s_waitcnt lgkmcnt(0)" ::: "memory");  // writes visible within wave
    bf16x8 pf = *reinterpret_cast<const bf16x8*>(&Pl[wid][r16][g * 8]);

    #pragma unroll
    for (int db = 0; db < 4; ++db) {
      u16x8 vu;
      #pragma unroll
      for (int jj = 0; jj < 8; ++jj)
        vu[jj] = V[(size_t)(kvb + 8 * g + jj) * DD + db * 16 + r16];
      bf16x8 vf = __builtin_bit_cast(bf16x8, vu);
      yacc[db] = mfma16(pf, vf, yacc[db]);
    }
    asm volatile("s_waitcnt lgkmcnt(0)" ::: "memory");  // P reads done before next overwrite
  }

  const int b = bh >> 4, h = bh & 15;
  #pragma unroll
  for (int db = 0; db < 4; ++db) {
    #pragma unroll
    for (int r = 0; r < 4; ++r) {
      int q = qw + 4 * g + r;
      float y = yacc[db][r] / lrow[r];
      yb[((size_t)b * TT + q) * CCH + h * DD + db * 16 + r16] = f2bf(y);
    }
  }
}

// ---------------- launcher ----------------

extern "C" void kernel_launch(void* const* d_in, const int* in_sizes, int n_in,
                              void* d_out, int out_size, void* d_ws, size_t ws_size,
                              hipStream_t stream) {
  const float* x      = (const float*)d_in[0];
  const float* w_attn = (const float*)d_in[1];
  const float* b_attn = (const float*)d_in[2];
  const float* w_proj = (const float*)d_in[3];
  const float* b_proj = (const float*)d_in[4];
  float* out = (float*)d_out;
  char* ws = (char*)d_ws;

  unsigned short* xb  = (unsigned short*)(ws + 0);          // 16 MB
  unsigned short* wat = (unsigned short*)(ws + 16777216);   // 6 MB  [3072][1024]
  unsigned short* wpt = (unsigned short*)(ws + 23068672);   // 2 MB  [1024][1024]
  unsigned short* qb  = (unsigned short*)(ws + 25165824);   // 16 MB [B,H,T,D]
  unsigned short* kb  = (unsigned short*)(ws + 41943040);   // 16 MB
  unsigned short* vb  = (unsigned short*)(ws + 58720256);   // 16 MB
  unsigned short* yb  = (unsigned short*)(ws + 75497472);   // 16 MB [B,T,C]

  // 1. conversions
  cvt_f32_bf16<<<(8192 * 1024 / 4 + 255) / 256, 256, 0, stream>>>(x, xb, 8192 * 1024 / 4);
  transpose_cvt<<<dim3(3072 / 32, 32), 256, 0, stream>>>(w_attn, wat, 3072);
  transpose_cvt<<<dim3(1024 / 32, 32), 256, 0, stream>>>(w_proj, wpt, 1024);

  // 2. QKV GEMM  [8192 x 3072]
  gemm_bf16<0><<<dim3(3072 / 128, 8192 / 128), 256, 0, stream>>>(
      xb, wat, b_attn, nullptr, qb, kb, vb, 1024);

  // 3. attention
  attn_kernel<<<dim3(TT / 64, 4 * HB), 256, 0, stream>>>(qb, kb, vb, yb);

  // 4. output projection [8192 x 1024]
  gemm_bf16<1><<<dim3(1024 / 128, 8192 / 128), 256, 0, stream>>>(
      yb, wpt, b_proj, out, nullptr, nullptr, nullptr, 1024);
}

// Round 2
// 441.805 us; speedup vs baseline: 1.0297x; 1.0297x over previous
//
#include <hip/hip_runtime.h>
#include <hip/hip_bf16.h>

typedef __bf16 bf16x8 __attribute__((ext_vector_type(8)));
typedef float f32x4 __attribute__((ext_vector_type(4)));
typedef unsigned short u16x8 __attribute__((ext_vector_type(8)));
typedef unsigned short u16x4 __attribute__((ext_vector_type(4)));

#define HB 16
#define TT 2048
#define CCH 1024
#define DD 64

__device__ __forceinline__ unsigned short f2bf(float f) {
  union { __hip_bfloat16 h; unsigned short u; } cv;
  cv.h = __float2bfloat16(f);
  return cv.u;
}

__device__ __forceinline__ f32x4 mfma16(bf16x8 a, bf16x8 b, f32x4 c) {
  return __builtin_amdgcn_mfma_f32_16x16x32_bf16(a, b, c, 0, 0, 0);
}

// ---------------- conversion kernels ----------------

__global__ __launch_bounds__(256) void cvt_f32_bf16(const float* __restrict__ in,
                                                    unsigned short* __restrict__ out,
                                                    int n4) {
  int i = blockIdx.x * 256 + threadIdx.x;
  if (i >= n4) return;
  float4 v = reinterpret_cast<const float4*>(in)[i];
  u16x4 o;
  o.x = f2bf(v.x); o.y = f2bf(v.y); o.z = f2bf(v.z); o.w = f2bf(v.w);
  *reinterpret_cast<u16x4*>(out + (size_t)i * 4) = o;
}

// w: [1024 x N] fp32  ->  wt: [N x 1024] bf16 (transposed)
__global__ __launch_bounds__(256) void transpose_cvt(const float* __restrict__ w,
                                                     unsigned short* __restrict__ wt,
                                                     int N) {
  __shared__ unsigned short t[32][33];
  int nb = blockIdx.x * 32, kb = blockIdx.y * 32;
  int tx = threadIdx.x & 31, ty = threadIdx.x >> 5;  // ty 0..7
  #pragma unroll
  for (int r = 0; r < 32; r += 8)
    t[ty + r][tx] = f2bf(w[(size_t)(kb + ty + r) * N + nb + tx]);
  __syncthreads();
  #pragma unroll
  for (int r = 0; r < 32; r += 8)
    wt[(size_t)(nb + ty + r) * 1024 + kb + tx] = t[tx][ty + r];
}

// ---------------- GEMM: C = A @ Bt^T (+bias), bf16 in, fp32 acc ----------------
// A: [M x K] bf16 row-major. Bt: [N x K] bf16 row-major (i.e. B transposed).
// EPI 0: scatter q/k -> [B,H,T,D] bf16 (q scaled 0.125), v -> TRANSPOSED [B,H,D,T].
// EPI 1: fp32 out (N=1024) + bias.

template <int EPI>
__global__ __launch_bounds__(256) void gemm_bf16(
    const unsigned short* __restrict__ A,
    const unsigned short* __restrict__ Bt,
    const float* __restrict__ bias,
    float* __restrict__ outf,
    unsigned short* __restrict__ qb,
    unsigned short* __restrict__ kb,
    unsigned short* __restrict__ vt,
    int Ktot) {
  __shared__ unsigned short As[128][72];
  __shared__ unsigned short Bs[128][72];
  const int tid = threadIdx.x;
  const int lane = tid & 63;
  const int wid = tid >> 6;
  const int r16 = lane & 15, g = lane >> 4;
  const int wm = wid >> 1, wn = wid & 1;
  const int m0 = blockIdx.y * 128, n0 = blockIdx.x * 128;

  f32x4 acc[4][4];
  #pragma unroll
  for (int i = 0; i < 4; ++i)
    #pragma unroll
    for (int j = 0; j < 4; ++j) acc[i][j] = (f32x4){0.f, 0.f, 0.f, 0.f};

  for (int kt = 0; kt < Ktot; kt += 64) {
    #pragma unroll
    for (int it = 0; it < 4; ++it) {
      int chunk = it * 256 + tid;
      int row = chunk >> 3, c8 = (chunk & 7) * 8;
      *reinterpret_cast<u16x8*>(&As[row][c8]) =
          *reinterpret_cast<const u16x8*>(&A[(size_t)(m0 + row) * Ktot + kt + c8]);
      *reinterpret_cast<u16x8*>(&Bs[row][c8]) =
          *reinterpret_cast<const u16x8*>(&Bt[(size_t)(n0 + row) * Ktot + kt + c8]);
    }
    __syncthreads();
    #pragma unroll
    for (int kk = 0; kk < 64; kk += 32) {
      bf16x8 af[4], bfr[4];
      #pragma unroll
      for (int i = 0; i < 4; ++i)
        af[i] = *reinterpret_cast<const bf16x8*>(&As[wm * 64 + i * 16 + r16][kk + g * 8]);
      #pragma unroll
      for (int j = 0; j < 4; ++j)
        bfr[j] = *reinterpret_cast<const bf16x8*>(&Bs[wn * 64 + j * 16 + r16][kk + g * 8]);
      #pragma unroll
      for (int i = 0; i < 4; ++i)
        #pragma unroll
        for (int j = 0; j < 4; ++j)
          acc[i][j] = mfma16(af[i], bfr[j], acc[i][j]);
    }
    __syncthreads();
  }

  #pragma unroll
  for (int i = 0; i < 4; ++i) {
    #pragma unroll
    for (int j = 0; j < 4; ++j) {
      const int n = n0 + wn * 64 + j * 16 + r16;
      const int mbase = m0 + wm * 64 + i * 16 + g * 4;
      const float bi = bias[n];
      if (EPI == 1) {
        #pragma unroll
        for (int r = 0; r < 4; ++r)
          outf[(size_t)(mbase + r) * 1024 + n] = acc[i][j][r] + bi;
      } else {
        const int which = n >> 10;
        const int cc2 = n & 1023;
        const int h = cc2 >> 6, d = cc2 & 63;
        const int b = mbase >> 11, t = mbase & 2047;
        if (which == 2) {
          // V transposed: [b][h][d][t], 4 consecutive t per lane -> one 8B store
          u16x4 o;
          #pragma unroll
          for (int r = 0; r < 4; ++r) o[r] = f2bf(acc[i][j][r] + bi);
          *reinterpret_cast<u16x4*>(
              &vt[(((size_t)b * HB + h) * DD + d) * TT + t]) = o;
        } else {
          unsigned short* dst = (which == 0) ? qb : kb;
          const float sc = (which == 0) ? 0.125f : 1.0f;  // fold 1/sqrt(64) into q
          #pragma unroll
          for (int r = 0; r < 4; ++r)
            dst[(((size_t)b * HB + h) * TT + (t + r)) * DD + d] =
                f2bf((acc[i][j][r] + bi) * sc);
        }
      }
    }
  }
}

// ---------------- flash attention ----------------
// grid: (16, B*H), 512 thr = 8 waves. Triangle pairing: waves 0-3 -> q-tile i,
// waves 4-7 -> q-tile 31-i  => uniform work per block. Each wave: 16 q-rows.
// KV tile = 64. V is read from the transposed Vt [B,H,D,T] with vector loads.

__global__ __launch_bounds__(512) void attn_kernel(
    const unsigned short* __restrict__ qg_,
    const unsigned short* __restrict__ kg_,
    const unsigned short* __restrict__ vtg_,
    unsigned short* __restrict__ yb) {
  const int bh = blockIdx.y;
  const int wid = threadIdx.x >> 6;
  const int lane = threadIdx.x & 63;
  const int r16 = lane & 15, g = lane >> 4;
  const int qtile = (wid < 4) ? blockIdx.x : (31 - blockIdx.x);
  const int qw = qtile * 64 + (wid & 3) * 16;
  const unsigned short* Q = qg_ + (size_t)bh * TT * DD;
  const unsigned short* K = kg_ + (size_t)bh * TT * DD;
  const unsigned short* Vt = vtg_ + (size_t)bh * DD * TT;

  __shared__ unsigned short Pl[8][16][72];  // per-wave P staging (144B rows)

  // Q fragments (q pre-scaled by 0.125)
  bf16x8 qf0 = *reinterpret_cast<const bf16x8*>(&Q[(size_t)(qw + r16) * DD + g * 8]);
  bf16x8 qf1 = *reinterpret_cast<const bf16x8*>(&Q[(size_t)(qw + r16) * DD + 32 + g * 8]);

  f32x4 yacc[4];
  #pragma unroll
  for (int db = 0; db < 4; ++db) yacc[db] = (f32x4){0.f, 0.f, 0.f, 0.f};
  float mrow[4], lrow[4];
  #pragma unroll
  for (int r = 0; r < 4; ++r) { mrow[r] = -1e30f; lrow[r] = 0.f; }

  const int kvend = qw + 16;
  for (int kvb = 0; kvb < kvend; kvb += 64) {
    // ---- S = Q K^T for 16 q-rows x 64 kv-cols ----
    f32x4 s[4];
    #pragma unroll
    for (int c = 0; c < 4; ++c) {
      bf16x8 ka = *reinterpret_cast<const bf16x8*>(
          &K[(size_t)(kvb + c * 16 + r16) * DD + g * 8]);
      bf16x8 kbf = *reinterpret_cast<const bf16x8*>(
          &K[(size_t)(kvb + c * 16 + r16) * DD + 32 + g * 8]);
      f32x4 t = (f32x4){0.f, 0.f, 0.f, 0.f};
      t = mfma16(qf0, ka, t);
      t = mfma16(qf1, kbf, t);
      s[c] = t;
    }

    // ---- mask + online softmax (row = qw + 4g + r, col = kvb + c*16 + r16) ----
    const bool masked = (kvb + 63 > qw);
    float p[4][4], mx[4];
    #pragma unroll
    for (int r = 0; r < 4; ++r) {
      const int q = qw + 4 * g + r;
      #pragma unroll
      for (int c = 0; c < 4; ++c) {
        float v = s[c][r];
        if (masked && (kvb + c * 16 + r16 > q)) v = -1e30f;
        p[c][r] = v;
      }
      mx[r] = fmaxf(fmaxf(p[0][r], p[1][r]), fmaxf(p[2][r], p[3][r]));
    }
    #pragma unroll
    for (int sh = 1; sh < 16; sh <<= 1)
      #pragma unroll
      for (int r = 0; r < 4; ++r) mx[r] = fmaxf(mx[r], __shfl_xor(mx[r], sh));

    float al[4], rs[4];
    #pragma unroll
    for (int r = 0; r < 4; ++r) {
      const float mn = fmaxf(mrow[r], mx[r]);
      al[r] = __expf(mrow[r] - mn);
      mrow[r] = mn;
      #pragma unroll
      for (int c = 0; c < 4; ++c) p[c][r] = __expf(p[c][r] - mn);
      rs[r] = (p[0][r] + p[1][r]) + (p[2][r] + p[3][r]);
    }
    #pragma unroll
    for (int sh = 1; sh < 16; sh <<= 1)
      #pragma unroll
      for (int r = 0; r < 4; ++r) rs[r] += __shfl_xor(rs[r], sh);
    #pragma unroll
    for (int r = 0; r < 4; ++r) lrow[r] = lrow[r] * al[r] + rs[r];
    #pragma unroll
    for (int db = 0; db < 4; ++db)
      #pragma unroll
      for (int r = 0; r < 4; ++r) yacc[db][r] *= al[r];

    // ---- stage P (bf16) in per-wave LDS, reread as A-fragments ----
    #pragma unroll
    for (int c = 0; c < 4; ++c)
      #pragma unroll
      for (int r = 0; r < 4; ++r)
        Pl[wid][4 * g + r][c * 16 + r16] = f2bf(p[c][r]);
    asm volatile("s_waitcnt lgkmcnt(0)" ::: "memory");

    // ---- Y += P @ V  (V from transposed layout, vector loads) ----
    #pragma unroll
    for (int kk = 0; kk < 2; ++kk) {
      bf16x8 pf = *reinterpret_cast<const bf16x8*>(&Pl[wid][r16][kk * 32 + g * 8]);
      #pragma unroll
      for (int db = 0; db < 4; ++db) {
        bf16x8 vf = *reinterpret_cast<const bf16x8*>(
            &Vt[(size_t)(db * 16 + r16) * TT + kvb + kk * 32 + g * 8]);
        yacc[db] = mfma16(pf, vf, yacc[db]);
      }
    }
    asm volatile("s_waitcnt lgkmcnt(0)" ::: "memory");
  }

  const int b = bh >> 4, h = bh & 15;
  #pragma unroll
  for (int db = 0; db < 4; ++db) {
    #pragma unroll
    for (int r = 0; r < 4; ++r) {
      const int q = qw + 4 * g + r;
      const float y = yacc[db][r] / lrow[r];
      yb[((size_t)b * TT + q) * CCH + h * DD + db * 16 + r16] = f2bf(y);
    }
  }
}

// ---------------- launcher ----------------

extern "C" void kernel_launch(void* const* d_in, const int* in_sizes, int n_in,
                              void* d_out, int out_size, void* d_ws, size_t ws_size,
                              hipStream_t stream) {
  const float* x      = (const float*)d_in[0];
  const float* w_attn = (const float*)d_in[1];
  const float* b_attn = (const float*)d_in[2];
  const float* w_proj = (const float*)d_in[3];
  const float* b_proj = (const float*)d_in[4];
  float* out = (float*)d_out;
  char* ws = (char*)d_ws;

  unsigned short* xb  = (unsigned short*)(ws + 0);          // 16 MB
  unsigned short* wat = (unsigned short*)(ws + 16777216);   // 6 MB  [3072][1024]
  unsigned short* wpt = (unsigned short*)(ws + 23068672);   // 2 MB  [1024][1024]
  unsigned short* qb  = (unsigned short*)(ws + 25165824);   // 16 MB [B,H,T,D]
  unsigned short* kb  = (unsigned short*)(ws + 41943040);   // 16 MB [B,H,T,D]
  unsigned short* vt  = (unsigned short*)(ws + 58720256);   // 16 MB [B,H,D,T]
  unsigned short* yb  = (unsigned short*)(ws + 75497472);   // 16 MB [B,T,C]

  cvt_f32_bf16<<<(8192 * 1024 / 4 + 255) / 256, 256, 0, stream>>>(x, xb, 8192 * 1024 / 4);
  transpose_cvt<<<dim3(3072 / 32, 32), 256, 0, stream>>>(w_attn, wat, 3072);
  transpose_cvt<<<dim3(1024 / 32, 32), 256, 0, stream>>>(w_proj, wpt, 1024);

  gemm_bf16<0><<<dim3(3072 / 128, 8192 / 128), 256, 0, stream>>>(
      xb, wat, b_attn, nullptr, qb, kb, vt, 1024);

  attn_kernel<<<dim3(16, 4 * HB), 512, 0, stream>>>(qb, kb, vt, yb);

  gemm_bf16<1><<<dim3(1024 / 128, 8192 / 128), 256, 0, stream>>>(
      yb, wpt, b_proj, out, nullptr, nullptr, nullptr, 1024);
}

// Round 3
// 216.707 us; speedup vs baseline: 2.0992x; 2.0387x over previous
//
#include <hip/hip_runtime.h>
#include <hip/hip_bf16.h>

typedef __bf16 bf16x8 __attribute__((ext_vector_type(8)));
typedef float f32x4 __attribute__((ext_vector_type(4)));
typedef unsigned short u16x8 __attribute__((ext_vector_type(8)));
typedef unsigned short u16x4 __attribute__((ext_vector_type(4)));

#define HB 16
#define TT 2048
#define CCH 1024
#define DD 64

__device__ __forceinline__ unsigned short f2bf(float f) {
  union { __hip_bfloat16 h; unsigned short u; } cv;
  cv.h = __float2bfloat16(f);
  return cv.u;
}

__device__ __forceinline__ unsigned pack2(float lo, float hi) {
  return (unsigned)f2bf(lo) | ((unsigned)f2bf(hi) << 16);
}

__device__ __forceinline__ f32x4 mfma16(bf16x8 a, bf16x8 b, f32x4 c) {
  return __builtin_amdgcn_mfma_f32_16x16x32_bf16(a, b, c, 0, 0, 0);
}

// ---------------- conversion kernels ----------------

__global__ __launch_bounds__(256) void cvt_f32_bf16(const float* __restrict__ in,
                                                    unsigned short* __restrict__ out,
                                                    int n4) {
  int i = blockIdx.x * 256 + threadIdx.x;
  if (i >= n4) return;
  float4 v = reinterpret_cast<const float4*>(in)[i];
  u16x4 o;
  o.x = f2bf(v.x); o.y = f2bf(v.y); o.z = f2bf(v.z); o.w = f2bf(v.w);
  *reinterpret_cast<u16x4*>(out + (size_t)i * 4) = o;
}

// w: [1024 x N] fp32  ->  wt: [N x 1024] bf16 (transposed)
__global__ __launch_bounds__(256) void transpose_cvt(const float* __restrict__ w,
                                                     unsigned short* __restrict__ wt,
                                                     int N) {
  __shared__ unsigned short t[32][33];
  int nb = blockIdx.x * 32, kb = blockIdx.y * 32;
  int tx = threadIdx.x & 31, ty = threadIdx.x >> 5;  // ty 0..7
  #pragma unroll
  for (int r = 0; r < 32; r += 8)
    t[ty + r][tx] = f2bf(w[(size_t)(kb + ty + r) * N + nb + tx]);
  __syncthreads();
  #pragma unroll
  for (int r = 0; r < 32; r += 8)
    wt[(size_t)(nb + ty + r) * 1024 + kb + tx] = t[tx][ty + r];
}

// ---------------- GEMM: C = A @ Bt^T (+bias), bf16 in, fp32 acc ----------------

template <int EPI>
__global__ __launch_bounds__(256) void gemm_bf16(
    const unsigned short* __restrict__ A,
    const unsigned short* __restrict__ Bt,
    const float* __restrict__ bias,
    float* __restrict__ outf,
    unsigned short* __restrict__ qb,
    unsigned short* __restrict__ kb,
    unsigned short* __restrict__ vt,
    int Ktot) {
  __shared__ unsigned short As[128][72];
  __shared__ unsigned short Bs[128][72];
  const int tid = threadIdx.x;
  const int lane = tid & 63;
  const int wid = tid >> 6;
  const int r16 = lane & 15, g = lane >> 4;
  const int wm = wid >> 1, wn = wid & 1;
  const int m0 = blockIdx.y * 128, n0 = blockIdx.x * 128;

  f32x4 acc[4][4];
  #pragma unroll
  for (int i = 0; i < 4; ++i)
    #pragma unroll
    for (int j = 0; j < 4; ++j) acc[i][j] = (f32x4){0.f, 0.f, 0.f, 0.f};

  for (int kt = 0; kt < Ktot; kt += 64) {
    #pragma unroll
    for (int it = 0; it < 4; ++it) {
      int chunk = it * 256 + tid;
      int row = chunk >> 3, c8 = (chunk & 7) * 8;
      *reinterpret_cast<u16x8*>(&As[row][c8]) =
          *reinterpret_cast<const u16x8*>(&A[(size_t)(m0 + row) * Ktot + kt + c8]);
      *reinterpret_cast<u16x8*>(&Bs[row][c8]) =
          *reinterpret_cast<const u16x8*>(&Bt[(size_t)(n0 + row) * Ktot + kt + c8]);
    }
    __syncthreads();
    #pragma unroll
    for (int kk = 0; kk < 64; kk += 32) {
      bf16x8 af[4], bfr[4];
      #pragma unroll
      for (int i = 0; i < 4; ++i)
        af[i] = *reinterpret_cast<const bf16x8*>(&As[wm * 64 + i * 16 + r16][kk + g * 8]);
      #pragma unroll
      for (int j = 0; j < 4; ++j)
        bfr[j] = *reinterpret_cast<const bf16x8*>(&Bs[wn * 64 + j * 16 + r16][kk + g * 8]);
      #pragma unroll
      for (int i = 0; i < 4; ++i)
        #pragma unroll
        for (int j = 0; j < 4; ++j)
          acc[i][j] = mfma16(af[i], bfr[j], acc[i][j]);
    }
    __syncthreads();
  }

  #pragma unroll
  for (int i = 0; i < 4; ++i) {
    #pragma unroll
    for (int j = 0; j < 4; ++j) {
      const int n = n0 + wn * 64 + j * 16 + r16;
      const int mbase = m0 + wm * 64 + i * 16 + g * 4;
      const float bi = bias[n];
      if (EPI == 1) {
        #pragma unroll
        for (int r = 0; r < 4; ++r)
          outf[(size_t)(mbase + r) * 1024 + n] = acc[i][j][r] + bi;
      } else {
        const int which = n >> 10;
        const int cc2 = n & 1023;
        const int h = cc2 >> 6, d = cc2 & 63;
        const int b = mbase >> 11, t = mbase & 2047;
        if (which == 2) {
          u16x4 o;
          #pragma unroll
          for (int r = 0; r < 4; ++r) o[r] = f2bf(acc[i][j][r] + bi);
          *reinterpret_cast<u16x4*>(
              &vt[(((size_t)b * HB + h) * DD + d) * TT + t]) = o;
        } else {
          unsigned short* dst = (which == 0) ? qb : kb;
          const float sc = (which == 0) ? 0.125f : 1.0f;
          #pragma unroll
          for (int r = 0; r < 4; ++r)
            dst[(((size_t)b * HB + h) * TT + (t + r)) * DD + d] =
                f2bf((acc[i][j][r] + bi) * sc);
        }
      }
    }
  }
}

// ---------------- flash attention (swapped QK^T, shuffle-PV, shared KV LDS) ---
// grid (16, B*H), 256 thr = 4 waves. Block jb: part 0 = q-group jb (64 rows),
// part 1 = q-group 31-jb. nt(part0)=jb+1, nt(part1)=32-jb -> uniform 33 tiles.
// All 4 waves share staged K/V tiles in LDS (reg-staged, issue-early).

__global__ __launch_bounds__(256) void attn_kernel(
    const unsigned short* __restrict__ qg_,
    const unsigned short* __restrict__ kg_,
    const unsigned short* __restrict__ vtg_,
    unsigned short* __restrict__ yb) {
  const int bh = blockIdx.y;
  const int jb = blockIdx.x;
  const int tid = threadIdx.x;
  const int wid = tid >> 6;
  const int lane = tid & 63;
  const int r16 = lane & 15, g = lane >> 4;
  const unsigned short* Q = qg_ + (size_t)bh * TT * DD;
  const unsigned short* K = kg_ + (size_t)bh * TT * DD;
  const unsigned short* Vt = vtg_ + (size_t)bh * DD * TT;
  const int b = bh >> 4, h = bh & 15;

  __shared__ unsigned short Ks[64][72];  // kv rows x d, padded (144B = 9*16)
  __shared__ unsigned short Vs[64][72];  // d rows x kv, padded

  const int srow = tid >> 3;        // 0..31
  const int scol = (tid & 7) * 8;   // 0,8,..,56

  #pragma unroll
  for (int part = 0; part < 2; ++part) {
    const int qg0 = (part == 0) ? jb * 64 : (31 - jb) * 64;
    const int nt = (part == 0) ? (jb + 1) : (32 - jb);
    const int qw = qg0 + wid * 16;
    const int q = qw + r16;  // this lane's q row

    bf16x8 qf0 = *reinterpret_cast<const bf16x8*>(&Q[(size_t)q * DD + g * 8]);
    bf16x8 qf1 = *reinterpret_cast<const bf16x8*>(&Q[(size_t)q * DD + 32 + g * 8]);

    f32x4 yacc[4];
    #pragma unroll
    for (int db = 0; db < 4; ++db) yacc[db] = (f32x4){0.f, 0.f, 0.f, 0.f};
    float m = -1e30f, l = 0.f;

    // prologue: stage tile 0
    u16x8 kr0 = *reinterpret_cast<const u16x8*>(&K[(size_t)srow * DD + scol]);
    u16x8 kr1 = *reinterpret_cast<const u16x8*>(&K[(size_t)(32 + srow) * DD + scol]);
    u16x8 vr0 = *reinterpret_cast<const u16x8*>(&Vt[(size_t)srow * TT + scol]);
    u16x8 vr1 = *reinterpret_cast<const u16x8*>(&Vt[(size_t)(32 + srow) * TT + scol]);
    *reinterpret_cast<u16x8*>(&Ks[srow][scol]) = kr0;
    *reinterpret_cast<u16x8*>(&Ks[32 + srow][scol]) = kr1;
    *reinterpret_cast<u16x8*>(&Vs[srow][scol]) = vr0;
    *reinterpret_cast<u16x8*>(&Vs[32 + srow][scol]) = vr1;
    __syncthreads();

    for (int t = 0; t < nt; ++t) {
      const int kvb = t * 64;
      if (t + 1 < nt) {  // issue next-tile loads early; latency hides under compute
        const int nb = kvb + 64;
        kr0 = *reinterpret_cast<const u16x8*>(&K[(size_t)(nb + srow) * DD + scol]);
        kr1 = *reinterpret_cast<const u16x8*>(&K[(size_t)(nb + 32 + srow) * DD + scol]);
        vr0 = *reinterpret_cast<const u16x8*>(&Vt[(size_t)srow * TT + nb + scol]);
        vr1 = *reinterpret_cast<const u16x8*>(&Vt[(size_t)(32 + srow) * TT + nb + scol]);
      }

      // ---- S^T = K Q^T : lane holds S^T[kvb+c*16+4g+r][q] ----
      f32x4 s[4];
      #pragma unroll
      for (int c = 0; c < 4; ++c) {
        bf16x8 kfa = *reinterpret_cast<const bf16x8*>(&Ks[c * 16 + r16][g * 8]);
        bf16x8 kfb = *reinterpret_cast<const bf16x8*>(&Ks[c * 16 + r16][32 + g * 8]);
        f32x4 z = (f32x4){0.f, 0.f, 0.f, 0.f};
        z = mfma16(kfa, qf0, z);
        z = mfma16(kfb, qf1, z);
        s[c] = z;
      }

      // ---- mask + online softmax (per-lane scalar: one q per lane) ----
      float p[4][4];
      float mx = -1e30f;
      const bool diag = (kvb + 63 > qw);
      #pragma unroll
      for (int c = 0; c < 4; ++c)
        #pragma unroll
        for (int r = 0; r < 4; ++r) {
          float v = s[c][r];
          if (diag && (kvb + c * 16 + 4 * g + r > q)) v = -1e30f;
          p[c][r] = v;
          mx = fmaxf(mx, v);
        }
      mx = fmaxf(mx, __shfl_xor(mx, 16));
      mx = fmaxf(mx, __shfl_xor(mx, 32));
      const float mn = fmaxf(m, mx);
      const float al = __expf(m - mn);
      m = mn;
      float rs = 0.f;
      #pragma unroll
      for (int c = 0; c < 4; ++c)
        #pragma unroll
        for (int r = 0; r < 4; ++r) {
          p[c][r] = __expf(p[c][r] - mn);
          rs += p[c][r];
        }
      rs += __shfl_xor(rs, 16);
      rs += __shfl_xor(rs, 32);
      l = l * al + rs;
      #pragma unroll
      for (int db = 0; db < 4; ++db)
        #pragma unroll
        for (int r = 0; r < 4; ++r) yacc[db][r] *= al;

      // ---- pack P to bf16 pairs: pk[c][w] = kv (c*16+4g+2w, +1) for col q ----
      unsigned pk[4][2];
      #pragma unroll
      for (int c = 0; c < 4; ++c) {
        pk[c][0] = pack2(p[c][0], p[c][1]);
        pk[c][1] = pack2(p[c][2], p[c][3]);
      }

      // ---- PV: Y^T += Vt_tile @ P^T ; P^T B-frag built by 16 shuffles ----
      const int s0l = r16 + 16 * ((2 * g) & 3);
      const int s1l = r16 + 16 * ((2 * g + 1) & 3);
      #pragma unroll
      for (int kk = 0; kk < 2; ++kk) {
        unsigned a0 = __shfl((int)pk[2 * kk][0], s0l, 64);
        unsigned b0 = __shfl((int)pk[2 * kk + 1][0], s0l, 64);
        unsigned a1 = __shfl((int)pk[2 * kk][1], s0l, 64);
        unsigned b1 = __shfl((int)pk[2 * kk + 1][1], s0l, 64);
        unsigned a2 = __shfl((int)pk[2 * kk][0], s1l, 64);
        unsigned b2 = __shfl((int)pk[2 * kk + 1][0], s1l, 64);
        unsigned a3 = __shfl((int)pk[2 * kk][1], s1l, 64);
        unsigned b3 = __shfl((int)pk[2 * kk + 1][1], s1l, 64);
        union { unsigned w[4]; bf16x8 v; } pf;
        pf.w[0] = (g < 2) ? a0 : b0;
        pf.w[1] = (g < 2) ? a1 : b1;
        pf.w[2] = (g < 2) ? a2 : b2;
        pf.w[3] = (g < 2) ? a3 : b3;
        #pragma unroll
        for (int db = 0; db < 4; ++db) {
          bf16x8 vf = *reinterpret_cast<const bf16x8*>(
              &Vs[db * 16 + r16][kk * 32 + g * 8]);
          yacc[db] = mfma16(vf, pf.v, yacc[db]);
        }
      }

      __syncthreads();  // all waves done reading Ks/Vs
      if (t + 1 < nt) {
        *reinterpret_cast<u16x8*>(&Ks[srow][scol]) = kr0;
        *reinterpret_cast<u16x8*>(&Ks[32 + srow][scol]) = kr1;
        *reinterpret_cast<u16x8*>(&Vs[srow][scol]) = vr0;
        *reinterpret_cast<u16x8*>(&Vs[32 + srow][scol]) = vr1;
      }
      __syncthreads();  // staged tile visible
    }

    // ---- epilogue: y = yacc / l ; lane writes 4 bf16 per db (consecutive d) --
    const float rl = 1.0f / l;
    #pragma unroll
    for (int db = 0; db < 4; ++db) {
      u16x4 o;
      #pragma unroll
      for (int r = 0; r < 4; ++r) o[r] = f2bf(yacc[db][r] * rl);
      *reinterpret_cast<u16x4*>(
          &yb[((size_t)b * TT + q) * CCH + h * DD + db * 16 + 4 * g]) = o;
    }
  }
}

// ---------------- launcher ----------------

extern "C" void kernel_launch(void* const* d_in, const int* in_sizes, int n_in,
                              void* d_out, int out_size, void* d_ws, size_t ws_size,
                              hipStream_t stream) {
  const float* x      = (const float*)d_in[0];
  const float* w_attn = (const float*)d_in[1];
  const float* b_attn = (const float*)d_in[2];
  const float* w_proj = (const float*)d_in[3];
  const float* b_proj = (const float*)d_in[4];
  float* out = (float*)d_out;
  char* ws = (char*)d_ws;

  unsigned short* xb  = (unsigned short*)(ws + 0);          // 16 MB
  unsigned short* wat = (unsigned short*)(ws + 16777216);   // 6 MB  [3072][1024]
  unsigned short* wpt = (unsigned short*)(ws + 23068672);   // 2 MB  [1024][1024]
  unsigned short* qb  = (unsigned short*)(ws + 25165824);   // 16 MB [B,H,T,D]
  unsigned short* kb  = (unsigned short*)(ws + 41943040);   // 16 MB [B,H,T,D]
  unsigned short* vt  = (unsigned short*)(ws + 58720256);   // 16 MB [B,H,D,T]
  unsigned short* yb  = (unsigned short*)(ws + 75497472);   // 16 MB [B,T,C]

  cvt_f32_bf16<<<(8192 * 1024 / 4 + 255) / 256, 256, 0, stream>>>(x, xb, 8192 * 1024 / 4);
  transpose_cvt<<<dim3(3072 / 32, 32), 256, 0, stream>>>(w_attn, wat, 3072);
  transpose_cvt<<<dim3(1024 / 32, 32), 256, 0, stream>>>(w_proj, wpt, 1024);

  gemm_bf16<0><<<dim3(3072 / 128, 8192 / 128), 256, 0, stream>>>(
      xb, wat, b_attn, nullptr, qb, kb, vt, 1024);

  attn_kernel<<<dim3(16, 4 * HB), 256, 0, stream>>>(qb, kb, vt, yb);

  gemm_bf16<1><<<dim3(1024 / 128, 8192 / 128), 256, 0, stream>>>(
      yb, wpt, b_proj, out, nullptr, nullptr, nullptr, 1024);
}

// Round 4
// 194.786 us; speedup vs baseline: 2.3354x; 1.1125x over previous
//
#include <hip/hip_runtime.h>
#include <hip/hip_bf16.h>

typedef __bf16 bf16x8 __attribute__((ext_vector_type(8)));
typedef float f32x4 __attribute__((ext_vector_type(4)));
typedef unsigned short u16x8 __attribute__((ext_vector_type(8)));
typedef unsigned short u16x4 __attribute__((ext_vector_type(4)));

#define HB 16
#define TT 2048
#define CCH 1024
#define DD 64

#define AS1 __attribute__((address_space(1)))
#define AS3 __attribute__((address_space(3)))
#define GL16(gp, lp) __builtin_amdgcn_global_load_lds((const AS1 void*)(gp), (AS3 void*)(lp), 16, 0, 0)

__device__ __forceinline__ unsigned short f2bf(float f) {
  union { __hip_bfloat16 h; unsigned short u; } cv;
  cv.h = __float2bfloat16(f);
  return cv.u;
}

__device__ __forceinline__ unsigned pack2(float lo, float hi) {
  return (unsigned)f2bf(lo) | ((unsigned)f2bf(hi) << 16);
}

__device__ __forceinline__ f32x4 mfma16(bf16x8 a, bf16x8 b, f32x4 c) {
  return __builtin_amdgcn_mfma_f32_16x16x32_bf16(a, b, c, 0, 0, 0);
}

// ---------------- conversion kernels ----------------

__global__ __launch_bounds__(256) void cvt_f32_bf16(const float* __restrict__ in,
                                                    unsigned short* __restrict__ out,
                                                    int n4) {
  int i = blockIdx.x * 256 + threadIdx.x;
  if (i >= n4) return;
  float4 v = reinterpret_cast<const float4*>(in)[i];
  u16x4 o;
  o.x = f2bf(v.x); o.y = f2bf(v.y); o.z = f2bf(v.z); o.w = f2bf(v.w);
  *reinterpret_cast<u16x4*>(out + (size_t)i * 4) = o;
}

// w: [1024 x N] fp32  ->  wt: [N x 1024] bf16 (transposed)
__global__ __launch_bounds__(256) void transpose_cvt(const float* __restrict__ w,
                                                     unsigned short* __restrict__ wt,
                                                     int N) {
  __shared__ unsigned short t[32][33];
  int nb = blockIdx.x * 32, kb = blockIdx.y * 32;
  int tx = threadIdx.x & 31, ty = threadIdx.x >> 5;  // ty 0..7
  #pragma unroll
  for (int r = 0; r < 32; r += 8)
    t[ty + r][tx] = f2bf(w[(size_t)(kb + ty + r) * N + nb + tx]);
  __syncthreads();
  #pragma unroll
  for (int r = 0; r < 32; r += 8)
    wt[(size_t)(nb + ty + r) * 1024 + kb + tx] = t[tx][ty + r];
}

// ---------------- GEMM (m97 structure): C = A @ Bt^T (+bias) ----------------
// Linear LDS tiles [128][64] bf16, global_load_lds width 16, XOR-swizzled
// source chunks + XOR'd ds_read columns (conflict-free, rule #21).
// EPI 0: scatter q/k -> [B,H,T,D] (q scaled 0.125*log2e), v -> [B,H,D,T].
// EPI 1: fp32 out + bias.

template <int EPI>
__global__ __launch_bounds__(256) void gemm_bf16(
    const unsigned short* __restrict__ A,
    const unsigned short* __restrict__ Bt,
    const float* __restrict__ bias,
    float* __restrict__ outf,
    unsigned short* __restrict__ qb,
    unsigned short* __restrict__ kb,
    unsigned short* __restrict__ vt) {
  __shared__ unsigned short As[8192];  // [128][64] linear
  __shared__ unsigned short Bs[8192];
  const int tid = threadIdx.x;
  const int lane = tid & 63;
  const int wid = tid >> 6;
  const int r16 = lane & 15, g = lane >> 4;
  const int wm = wid >> 1, wn = wid & 1;
  const int m0 = blockIdx.y * 128, n0 = blockIdx.x * 128;
  const int srow = tid >> 3;                 // 0..31 (+32 per instr)
  const int schx = (tid & 7) ^ (srow & 7);   // XOR-swizzled source chunk

  f32x4 acc[4][4];
  #pragma unroll
  for (int i = 0; i < 4; ++i)
    #pragma unroll
    for (int j = 0; j < 4; ++j) acc[i][j] = (f32x4){0.f, 0.f, 0.f, 0.f};

  const int rx = r16 & 7;

  for (int kt = 0; kt < 1024; kt += 64) {
    #pragma unroll
    for (int i = 0; i < 4; ++i) {
      const int row = i * 32 + srow;
      GL16(A + (size_t)(m0 + row) * 1024 + kt + schx * 8, As + i * 2048 + tid * 8);
    }
    #pragma unroll
    for (int i = 0; i < 4; ++i) {
      const int row = i * 32 + srow;
      GL16(Bt + (size_t)(n0 + row) * 1024 + kt + schx * 8, Bs + i * 2048 + tid * 8);
    }
    __syncthreads();  // compiler drains vmcnt before barrier -> tiles ready
    #pragma unroll
    for (int h = 0; h < 2; ++h) {
      bf16x8 af[4], bfr[4];
      #pragma unroll
      for (int i = 0; i < 4; ++i)
        af[i] = *reinterpret_cast<const bf16x8*>(
            &As[(wm * 64 + i * 16 + r16) * 64 + ((g + 4 * h) ^ rx) * 8]);
      #pragma unroll
      for (int j = 0; j < 4; ++j)
        bfr[j] = *reinterpret_cast<const bf16x8*>(
            &Bs[(wn * 64 + j * 16 + r16) * 64 + ((g + 4 * h) ^ rx) * 8]);
      #pragma unroll
      for (int i = 0; i < 4; ++i)
        #pragma unroll
        for (int j = 0; j < 4; ++j)
          acc[i][j] = mfma16(af[i], bfr[j], acc[i][j]);
    }
    __syncthreads();
  }

  #pragma unroll
  for (int i = 0; i < 4; ++i) {
    #pragma unroll
    for (int j = 0; j < 4; ++j) {
      const int n = n0 + wn * 64 + j * 16 + r16;
      const int mbase = m0 + wm * 64 + i * 16 + g * 4;
      const float bi = bias[n];
      if (EPI == 1) {
        #pragma unroll
        for (int r = 0; r < 4; ++r)
          outf[(size_t)(mbase + r) * 1024 + n] = acc[i][j][r] + bi;
      } else {
        const int which = n >> 10;
        const int cc2 = n & 1023;
        const int h = cc2 >> 6, d = cc2 & 63;
        const int b = mbase >> 11, t = mbase & 2047;
        if (which == 2) {
          u16x4 o;
          #pragma unroll
          for (int r = 0; r < 4; ++r) o[r] = f2bf(acc[i][j][r] + bi);
          *reinterpret_cast<u16x4*>(
              &vt[(((size_t)b * HB + h) * DD + d) * TT + t]) = o;
        } else {
          unsigned short* dst = (which == 0) ? qb : kb;
          // q folded scale: 1/sqrt(64) * log2(e)  (exp2-domain softmax)
          const float sc = (which == 0) ? 0.18033688011112042f : 1.0f;
          #pragma unroll
          for (int r = 0; r < 4; ++r)
            dst[(((size_t)b * HB + h) * TT + (t + r)) * DD + d] =
                f2bf((acc[i][j][r] + bi) * sc);
        }
      }
    }
  }
}

// ---------------- flash attention ----------------
// grid (8, B*H), 512 thr = 8 waves, KVBLK=128, wave owns 16 q-rows (one q per
// lane via swapped QK^T). K/V double-buffered in LDS via global_load_lds with
// XOR-swizzled source; deep prefetch (issue t+2 after per-tile barrier).
// Triangle pairing: part0 = q-group jb, part1 = q-group 15-jb -> 17 tiles/block.

__global__ __launch_bounds__(512, 2) void attn_kernel(
    const unsigned short* __restrict__ qg_,
    const unsigned short* __restrict__ kg_,
    const unsigned short* __restrict__ vtg_,
    unsigned short* __restrict__ yb) {
  const int bh = blockIdx.y;
  const int jb = blockIdx.x;
  const int tid = threadIdx.x;
  const int wid = tid >> 6;
  const int lane = tid & 63;
  const int r16 = lane & 15, g = lane >> 4;
  const unsigned short* Q = qg_ + (size_t)bh * TT * DD;
  const unsigned short* K = kg_ + (size_t)bh * TT * DD;
  const unsigned short* Vt = vtg_ + (size_t)bh * DD * TT;
  const int b = bh >> 4, h = bh & 15;

  // buf: [K 8192 elems = [128][64]] [V 8192 elems = [64][128]]
  __shared__ unsigned short smem[2][16384];

  const int krow0 = tid >> 3;                    // 0..63 (+64 per instr)
  const int kchx = (tid & 7) ^ (krow0 & 7);      // K source chunk (XOR swz)
  const int vd0 = tid >> 4;                      // 0..31 (+32 per instr)
  const int vchx = (tid & 15) ^ (vd0 & 7);       // V source chunk (XOR swz)
  const int rx = r16 & 7;

#define STAGE(bi, kvb_) do {                                                      \
    unsigned short* sb_ = &smem[bi][0];                                           \
    const unsigned short* gk_ = K + (size_t)(kvb_) * DD;                          \
    GL16(gk_ + (size_t)krow0 * DD + kchx * 8,              sb_ + tid * 8);        \
    GL16(gk_ + (size_t)(64 + krow0) * DD + kchx * 8,       sb_ + 4096 + tid * 8); \
    GL16(Vt + (size_t)vd0 * TT + (kvb_) + vchx * 8,        sb_ + 8192 + tid * 8); \
    GL16(Vt + (size_t)(32 + vd0) * TT + (kvb_) + vchx * 8, sb_ + 12288 + tid * 8);\
  } while (0)

  #pragma unroll
  for (int part = 0; part < 2; ++part) {
    const int qg0 = (part == 0) ? jb * 128 : (15 - jb) * 128;
    const int nt = (part == 0) ? (jb + 1) : (16 - jb);
    const int qw = qg0 + wid * 16;
    const int q = qw + r16;  // this lane's q row

    bf16x8 qf0 = *reinterpret_cast<const bf16x8*>(&Q[(size_t)q * DD + g * 8]);
    bf16x8 qf1 = *reinterpret_cast<const bf16x8*>(&Q[(size_t)q * DD + 32 + g * 8]);

    f32x4 yacc[4];
    #pragma unroll
    for (int db = 0; db < 4; ++db) yacc[db] = (f32x4){0.f, 0.f, 0.f, 0.f};
    float m = -1e30f, l = 0.f;

    STAGE(0, qg0 * 0);  // tile 0 (kvb=0)
    if (nt > 1) {
      STAGE(1, 128);
      asm volatile("s_waitcnt vmcnt(4)" ::: "memory");
    } else {
      asm volatile("s_waitcnt vmcnt(0)" ::: "memory");
    }
    __builtin_amdgcn_s_barrier();

    for (int t = 0; t < nt; ++t) {
      const int kvb = t * 128;
      const unsigned short* sK = &smem[t & 1][0];
      const unsigned short* sV = &smem[t & 1][8192];

      // ---- S^T = K Q^T : lane holds S^T[kvb + c*16 + 4g + r][q] ----
      float s[8][4];
      #pragma unroll
      for (int c = 0; c < 8; ++c) {
        bf16x8 kfa = *reinterpret_cast<const bf16x8*>(
            &sK[(c * 16 + r16) * 64 + (g ^ rx) * 8]);
        bf16x8 kfb = *reinterpret_cast<const bf16x8*>(
            &sK[(c * 16 + r16) * 64 + ((g + 4) ^ rx) * 8]);
        f32x4 z = (f32x4){0.f, 0.f, 0.f, 0.f};
        z = mfma16(kfa, qf0, z);
        z = mfma16(kfb, qf1, z);
        #pragma unroll
        for (int r = 0; r < 4; ++r) s[c][r] = z[r];
      }

      // ---- mask (last tile only) + max ----
      float mx = -1e30f;
      if (t == nt - 1) {
        #pragma unroll
        for (int c = 0; c < 8; ++c)
          #pragma unroll
          for (int r = 0; r < 4; ++r) {
            if (kvb + c * 16 + 4 * g + r > q) s[c][r] = -1e30f;
            mx = fmaxf(mx, s[c][r]);
          }
      } else {
        #pragma unroll
        for (int c = 0; c < 8; ++c)
          #pragma unroll
          for (int r = 0; r < 4; ++r) mx = fmaxf(mx, s[c][r]);
      }
      mx = fmaxf(mx, __shfl_xor(mx, 16));
      mx = fmaxf(mx, __shfl_xor(mx, 32));

      // ---- defer-max (T13, exp2 domain, THR=8) ----
      if (!__all(mx <= m + 8.f)) {
        const float mn = fmaxf(m, mx);
        const float al = exp2f(m - mn);
        m = mn;
        l *= al;
        #pragma unroll
        for (int db = 0; db < 4; ++db)
          #pragma unroll
          for (int r = 0; r < 4; ++r) yacc[db][r] *= al;
      }
      float rs = 0.f;
      #pragma unroll
      for (int c = 0; c < 8; ++c)
        #pragma unroll
        for (int r = 0; r < 4; ++r) {
          s[c][r] = exp2f(s[c][r] - m);
          rs += s[c][r];
        }
      rs += __shfl_xor(rs, 16);
      rs += __shfl_xor(rs, 32);
      l += rs;

      // ---- PV: per kk, build P^T B-frag by shuffles, A = V from LDS ----
      const int s0l = r16 + 16 * ((2 * g) & 3);
      const int s1l = r16 + 16 * ((2 * g + 1) & 3);
      #pragma unroll
      for (int kk = 0; kk < 4; ++kk) {
        const unsigned x0 = pack2(s[2 * kk][0], s[2 * kk][1]);
        const unsigned x1 = pack2(s[2 * kk][2], s[2 * kk][3]);
        const unsigned y0 = pack2(s[2 * kk + 1][0], s[2 * kk + 1][1]);
        const unsigned y1 = pack2(s[2 * kk + 1][2], s[2 * kk + 1][3]);
        unsigned a0 = __shfl((int)x0, s0l, 64);
        unsigned b0 = __shfl((int)y0, s0l, 64);
        unsigned a1 = __shfl((int)x1, s0l, 64);
        unsigned b1 = __shfl((int)y1, s0l, 64);
        unsigned a2 = __shfl((int)x0, s1l, 64);
        unsigned b2 = __shfl((int)y0, s1l, 64);
        unsigned a3 = __shfl((int)x1, s1l, 64);
        unsigned b3 = __shfl((int)y1, s1l, 64);
        union { unsigned w[4]; bf16x8 v; } pf;
        pf.w[0] = (g < 2) ? a0 : b0;
        pf.w[1] = (g < 2) ? a1 : b1;
        pf.w[2] = (g < 2) ? a2 : b2;
        pf.w[3] = (g < 2) ? a3 : b3;
        #pragma unroll
        for (int db = 0; db < 4; ++db) {
          bf16x8 vf = *reinterpret_cast<const bf16x8*>(
              &sV[(db * 16 + r16) * 128 + ((kk * 4 + g) ^ rx) * 8]);
          yacc[db] = mfma16(vf, pf.v, yacc[db]);
        }
      }

      __syncthreads();  // all waves done with buf[t&1]; drains in-flight t+1
      if (t + 2 < nt) STAGE(t & 1, (t + 2) * 128);
    }

    // ---- epilogue: y = yacc / l ----
    const float rl = 1.0f / l;
    #pragma unroll
    for (int db = 0; db < 4; ++db) {
      u16x4 o;
      #pragma unroll
      for (int r = 0; r < 4; ++r) o[r] = f2bf(yacc[db][r] * rl);
      *reinterpret_cast<u16x4*>(
          &yb[((size_t)b * TT + q) * CCH + h * DD + db * 16 + 4 * g]) = o;
    }
  }
#undef STAGE
}

// ---------------- launcher ----------------

extern "C" void kernel_launch(void* const* d_in, const int* in_sizes, int n_in,
                              void* d_out, int out_size, void* d_ws, size_t ws_size,
                              hipStream_t stream) {
  const float* x      = (const float*)d_in[0];
  const float* w_attn = (const float*)d_in[1];
  const float* b_attn = (const float*)d_in[2];
  const float* w_proj = (const float*)d_in[3];
  const float* b_proj = (const float*)d_in[4];
  float* out = (float*)d_out;
  char* ws = (char*)d_ws;

  unsigned short* xb  = (unsigned short*)(ws + 0);          // 16 MB
  unsigned short* wat = (unsigned short*)(ws + 16777216);   // 6 MB  [3072][1024]
  unsigned short* wpt = (unsigned short*)(ws + 23068672);   // 2 MB  [1024][1024]
  unsigned short* qb  = (unsigned short*)(ws + 25165824);   // 16 MB [B,H,T,D]
  unsigned short* kb  = (unsigned short*)(ws + 41943040);   // 16 MB [B,H,T,D]
  unsigned short* vt  = (unsigned short*)(ws + 58720256);   // 16 MB [B,H,D,T]
  unsigned short* yb  = (unsigned short*)(ws + 75497472);   // 16 MB [B,T,C]

  cvt_f32_bf16<<<(8192 * 1024 / 4 + 255) / 256, 256, 0, stream>>>(x, xb, 8192 * 1024 / 4);
  transpose_cvt<<<dim3(3072 / 32, 32), 256, 0, stream>>>(w_attn, wat, 3072);
  transpose_cvt<<<dim3(1024 / 32, 32), 256, 0, stream>>>(w_proj, wpt, 1024);

  gemm_bf16<0><<<dim3(3072 / 128, 8192 / 128), 256, 0, stream>>>(
      xb, wat, b_attn, nullptr, qb, kb, vt);

  attn_kernel<<<dim3(8, 4 * HB), 512, 0, stream>>>(qb, kb, vt, yb);

  gemm_bf16<1><<<dim3(1024 / 128, 8192 / 128), 256, 0, stream>>>(
      yb, wpt, b_proj, out, nullptr, nullptr, nullptr);
}